// Round 16
// baseline (1201.065 us; speedup 1.0000x reference)
//
#include <hip/hip_runtime.h>

#define TT 512
#define NB 128   // batch
#define DD 128
#define HH 64
#define CC 45

__device__ __forceinline__ float sigf(float x) { return 1.0f / (1.0f + __expf(-x)); }

// LDS-only barrier: syncs LDS visibility WITHOUT draining vmcnt.
#define LDS_BAR() asm volatile("s_waitcnt lgkmcnt(0)\n\ts_barrier" ::: "memory")

// bf16 helpers (RN rounding), ushort carries the bit pattern.
__device__ __forceinline__ ushort f2bf(float x) {
    uint u = __float_as_uint(x);
    u += 0x7FFFu + ((u >> 16) & 1u);
    return (ushort)(u >> 16);
}
__device__ __forceinline__ float bf2f(ushort h) { return __uint_as_float(((uint)h) << 16); }

typedef short short8 __attribute__((ext_vector_type(8)));
typedef float f32x4 __attribute__((ext_vector_type(4)));

// packed bf16 pair convert (RNE): D[15:0]=bf16(a), D[31:16]=bf16(b)
__device__ __forceinline__ uint pkbf(float a, float b) {
    uint r; asm("v_cvt_pk_bf16_f32 %0, %1, %2" : "=v"(r) : "v"(a), "v"(b)); return r;
}
__device__ __forceinline__ float lo2f(uint p) { return __uint_as_float(p << 16); }
__device__ __forceinline__ float hi2f(uint p) { return __uint_as_float(p & 0xFFFF0000u); }
__device__ __forceinline__ short8 mk8(uint a, uint b, uint c, uint d) {
    union { uint u[4]; short8 s; } x; x.u[0]=a; x.u[1]=b; x.u[2]=c; x.u[3]=d; return x.s;
}
// split 8 floats into hi/lo bf16 short8 frags (hi=RNE, lo=RN(exact residual))
#define SPLIT8(o0,o1,o2,o3,o4,o5,o6,o7, H, L) { \
    const uint h0_ = pkbf(o0,o1), h1_ = pkbf(o2,o3), h2_ = pkbf(o4,o5), h3_ = pkbf(o6,o7); \
    const uint l0_ = pkbf((o0) - lo2f(h0_), (o1) - hi2f(h0_)); \
    const uint l1_ = pkbf((o2) - lo2f(h1_), (o3) - hi2f(h1_)); \
    const uint l2_ = pkbf((o4) - lo2f(h2_), (o5) - hi2f(h2_)); \
    const uint l3_ = pkbf((o6) - lo2f(h3_), (o7) - hi2f(h3_)); \
    H = mk8(h0_,h1_,h2_,h3_); L = mk8(l0_,l1_,l2_,l3_); }

// ---------------------------------------------------------------------------
// GEMM v2 via split-bf16 MFMA (R15, proven ~45us/dispatch).
// ---------------------------------------------------------------------------
__global__ __launch_bounds__(256, 2) void gemm_xz_mfma2(
    const float* __restrict__ A, const float* __restrict__ Wf,
    const float* __restrict__ Wb, const float* __restrict__ biasf,
    const float* __restrict__ biasb, float* __restrict__ Cout)
{
    __shared__ ushort Wh[128][136];
    __shared__ ushort Wl[128][136];

    const int tid = threadIdx.x;
    const int n0  = blockIdx.x * 128;
    const int m0  = blockIdx.y * 128;
    const float* W   = (n0 < 256) ? Wf : Wb;
    const float* bia = (n0 < 256) ? biasf : biasb;
    const int nc0 = n0 & 255;

    {
        const int r  = tid >> 1;
        const int cb = (tid & 1) * 64;
        #pragma unroll
        for (int i = 0; i < 16; ++i) {
            const int c = cb + i * 4;
            const float4 wv = *(const float4*)&W[(size_t)r * 256 + nc0 + c];
            const ushort h0 = (ushort)(__float_as_uint(wv.x) >> 16);
            const ushort h1 = (ushort)(__float_as_uint(wv.y) >> 16);
            const ushort h2 = (ushort)(__float_as_uint(wv.z) >> 16);
            const ushort h3 = (ushort)(__float_as_uint(wv.w) >> 16);
            Wh[c + 0][r] = h0; Wl[c + 0][r] = f2bf(wv.x - bf2f(h0));
            Wh[c + 1][r] = h1; Wl[c + 1][r] = f2bf(wv.y - bf2f(h1));
            Wh[c + 2][r] = h2; Wl[c + 2][r] = f2bf(wv.z - bf2f(h2));
            Wh[c + 3][r] = h3; Wl[c + 3][r] = f2bf(wv.w - bf2f(h3));
        }
    }
    __syncthreads();

    const int lane = tid & 63, wv_ = tid >> 6;
    const int fr = lane & 15, fg = lane >> 4;

    f32x4 acc[2][8];
    #pragma unroll
    for (int ms = 0; ms < 2; ++ms)
        #pragma unroll
        for (int nt = 0; nt < 8; ++nt) acc[ms][nt] = (f32x4){0.f, 0.f, 0.f, 0.f};

    #pragma unroll
    for (int ks = 0; ks < 4; ++ks) {
        const int kb = ks * 32 + fg * 8;
        short8 ah[2], al[2];
        #pragma unroll
        for (int ms = 0; ms < 2; ++ms) {
            const float* ap = &A[(size_t)(m0 + wv_ * 32 + ms * 16 + fr) * 128 + kb];
            const float4 va = *(const float4*)ap;
            const float4 vb = *(const float4*)(ap + 4);
            float v[8] = {va.x, va.y, va.z, va.w, vb.x, vb.y, vb.z, vb.w};
            #pragma unroll
            for (int j = 0; j < 8; ++j) {
                const ushort hj = (ushort)(__float_as_uint(v[j]) >> 16);
                ah[ms][j] = (short)hj;
                al[ms][j] = (short)f2bf(v[j] - bf2f(hj));
            }
        }
        #pragma unroll
        for (int nt = 0; nt < 8; ++nt) {
            const short8 bh = *(const short8*)&Wh[nt * 16 + fr][kb];
            const short8 bl = *(const short8*)&Wl[nt * 16 + fr][kb];
            acc[0][nt] = __builtin_amdgcn_mfma_f32_16x16x32_bf16(ah[0], bh, acc[0][nt], 0, 0, 0);
            acc[0][nt] = __builtin_amdgcn_mfma_f32_16x16x32_bf16(ah[0], bl, acc[0][nt], 0, 0, 0);
            acc[0][nt] = __builtin_amdgcn_mfma_f32_16x16x32_bf16(al[0], bh, acc[0][nt], 0, 0, 0);
            acc[1][nt] = __builtin_amdgcn_mfma_f32_16x16x32_bf16(ah[1], bh, acc[1][nt], 0, 0, 0);
            acc[1][nt] = __builtin_amdgcn_mfma_f32_16x16x32_bf16(ah[1], bl, acc[1][nt], 0, 0, 0);
            acc[1][nt] = __builtin_amdgcn_mfma_f32_16x16x32_bf16(al[1], bh, acc[1][nt], 0, 0, 0);
        }
    }

    #pragma unroll
    for (int nt = 0; nt < 8; ++nt) {
        const float bb = bia[nc0 + nt * 16 + fr];
        #pragma unroll
        for (int ms = 0; ms < 2; ++ms) {
            #pragma unroll
            for (int j = 0; j < 4; ++j) {
                const int mg = m0 + wv_ * 32 + ms * 16 + fg * 4 + j;
                Cout[(size_t)mg * 512 + n0 + nt * 16 + fr] = acc[ms][nt][j] + bb;
            }
        }
    }
}

// ---------------------------------------------------------------------------
// LSTM recurrence via MFMA. 16 blocks (2 dirs x 8 batch-groups of 16) x 256
// threads (4 waves). Per step, per wave: z-tile(16 batch x 16 gcol) for each
// of the 4 gates = 6 chained mfma_16x16x32_bf16 (split-bf16 hh+hl+lh over
// 2 k-halves), with xz as the accumulator init. All 4 gates of a (batch,col)
// state land in the SAME lane (C/D: row=batch=(lane>>4)*4+j, col=lane&15) ->
// gate math is pure per-lane VALU, no shuffles. U-frags: 16 short8 built via
// cvt chains (NOT single-load remat candidates -> RA keeps them; R12 gemm
// precedent). h redistribution: 4KB LDS transpose, pad-68 (conflict-free
// baseline), ONE LDS_BAR/step. This kills the two proven walls of the FMA
// recs: the 64KB/step LDS h-broadcast and the 64KB/step U re-fetch.
// Wall time = step latency x 512; only 16 CUs busy — chains are the scarce
// resource, not CUs.
// ---------------------------------------------------------------------------
__global__ __launch_bounds__(256, 1) void lstm_rec_mm(
    const float* __restrict__ xz, const float* __restrict__ Uf,
    const float* __restrict__ Ubw, float* __restrict__ hout)
{
    const int bid = blockIdx.x;         // 0..15
    const int dir = bid >> 3;
    const int b0  = (bid & 7) << 4;     // batch base (16 per block)
    const int tid = threadIdx.x;
    const int w    = tid >> 6;          // wave 0..3: h-cols [w*16, w*16+16)
    const int lane = tid & 63;
    const int fr = lane & 15;           // frag row/col index
    const int fg = lane >> 4;           // k-group (8 consecutive k)
    const float* U = dir ? Ubw : Uf;

    __shared__ float hbuf[2][16][68];   // [parity][batch][col], pad 68

    // ---- stage U B-frags (one-time): uh/ul for gate g, k-half kh ----
    // B-frag: lane holds U[kh*32 + fg*8 + i][g*64 + w*16 + fr], i=0..7
#define LDU(g, kh, H, L) short8 H, L; { \
    const float* up = U + (size_t)((kh)*32 + fg*8) * 256 + (g)*64 + w*16 + fr; \
    const float v0 = up[0*256], v1 = up[1*256], v2 = up[2*256], v3 = up[3*256]; \
    const float v4 = up[4*256], v5 = up[5*256], v6 = up[6*256], v7 = up[7*256]; \
    SPLIT8(v0,v1,v2,v3,v4,v5,v6,v7, H, L) }
    LDU(0,0, uh00, ul00)  LDU(0,1, uh01, ul01)
    LDU(1,0, uh10, ul10)  LDU(1,1, uh11, ul11)
    LDU(2,0, uh20, ul20)  LDU(2,1, uh21, ul21)
    LDU(3,0, uh30, ul30)  LDU(3,1, uh31, ul31)
#undef LDU

    // zero h buffers
    for (int i = tid; i < 2 * 16 * 68; i += 256) ((float*)hbuf)[i] = 0.f;
    f32x4 cst = (f32x4){0.f, 0.f, 0.f, 0.f};
    __syncthreads();

    // xz row base pointers for this lane's 4 batch rows (j = C/D reg index)
    const float* xr0 = xz + (size_t)(b0 + fg*4 + 0) * TT * 512 + dir * 256 + w*16 + fr;
    const float* xr1 = xz + (size_t)(b0 + fg*4 + 1) * TT * 512 + dir * 256 + w*16 + fr;
    const float* xr2 = xz + (size_t)(b0 + fg*4 + 2) * TT * 512 + dir * 256 + w*16 + fr;
    const float* xr3 = xz + (size_t)(b0 + fg*4 + 3) * TT * 512 + dir * 256 + w*16 + fr;
    float* hb0 = hout + (size_t)(b0 + fg*4 + 0) * TT * 128 + dir * 64 + w*16 + fr;
    float* hb1 = hout + (size_t)(b0 + fg*4 + 1) * TT * 128 + dir * 64 + w*16 + fr;
    float* hb2 = hout + (size_t)(b0 + fg*4 + 2) * TT * 128 + dir * 64 + w*16 + fr;
    float* hb3 = hout + (size_t)(b0 + fg*4 + 3) * TT * 128 + dir * 64 + w*16 + fr;

    int trow = dir ? (TT - 1) : 0;
    const int ts = dir ? -1 : 1;

    // xz for step 0 (xc_g[j] = xz[row j][gate g])
    f32x4 xcI, xcF, xcG, xcO;
    {
        const size_t o = (size_t)trow * 512;
        xcI = (f32x4){xr0[o+  0], xr1[o+  0], xr2[o+  0], xr3[o+  0]};
        xcF = (f32x4){xr0[o+ 64], xr1[o+ 64], xr2[o+ 64], xr3[o+ 64]};
        xcG = (f32x4){xr0[o+128], xr1[o+128], xr2[o+128], xr3[o+128]};
        xcO = (f32x4){xr0[o+192], xr1[o+192], xr2[o+192], xr3[o+192]};
    }

    int p = 0;
    for (int s = 0; s < TT; ++s) {
        const int pn = p ^ 1;
        const int trn = trow + ts;

        // prefetch next step's xz (used next iteration; never waited here)
        f32x4 xnI, xnF, xnG, xnO;
        if (s + 1 < TT) {
            const size_t o = (size_t)trn * 512;
            xnI = (f32x4){xr0[o+  0], xr1[o+  0], xr2[o+  0], xr3[o+  0]};
            xnF = (f32x4){xr0[o+ 64], xr1[o+ 64], xr2[o+ 64], xr3[o+ 64]};
            xnG = (f32x4){xr0[o+128], xr1[o+128], xr2[o+128], xr3[o+128]};
            xnO = (f32x4){xr0[o+192], xr1[o+192], xr2[o+192], xr3[o+192]};
        } else {
            xnI = xnF = xnG = xnO = (f32x4){0.f, 0.f, 0.f, 0.f};
        }

        // A-frag: h[batch=fr][16 k-cols] from LDS, split to bf16 hi/lo
        const float* hrow = &hbuf[p][fr][0];
        const float4 hA = *(const float4*)&hrow[fg*8];
        const float4 hB = *(const float4*)&hrow[fg*8 + 4];
        const float4 hC = *(const float4*)&hrow[32 + fg*8];
        const float4 hD = *(const float4*)&hrow[32 + fg*8 + 4];
        short8 ah0, al0, ah1, al1;
        SPLIT8(hA.x,hA.y,hA.z,hA.w, hB.x,hB.y,hB.z,hB.w, ah0, al0)
        SPLIT8(hC.x,hC.y,hC.z,hC.w, hD.x,hD.y,hD.z,hD.w, ah1, al1)

        // z-tiles: acc init = xz, then 6 chained MFMAs per gate
        f32x4 azi = xcI, azf = xcF, azg = xcG, azo = xcO;
#define MM(dst, H0, H1, L0, L1) \
        dst = __builtin_amdgcn_mfma_f32_16x16x32_bf16(ah0, H0, dst, 0,0,0); \
        dst = __builtin_amdgcn_mfma_f32_16x16x32_bf16(ah1, H1, dst, 0,0,0); \
        dst = __builtin_amdgcn_mfma_f32_16x16x32_bf16(ah0, L0, dst, 0,0,0); \
        dst = __builtin_amdgcn_mfma_f32_16x16x32_bf16(ah1, L1, dst, 0,0,0); \
        dst = __builtin_amdgcn_mfma_f32_16x16x32_bf16(al0, H0, dst, 0,0,0); \
        dst = __builtin_amdgcn_mfma_f32_16x16x32_bf16(al1, H1, dst, 0,0,0);
        MM(azi, uh00, uh01, ul00, ul01)
        MM(azf, uh10, uh11, ul10, ul11)
        MM(azg, uh20, uh21, ul20, ul21)
        MM(azo, uh30, uh31, ul30, ul31)
#undef MM

        // gates + state update + h out (per lane: 4 states, all gates in-lane)
#define GATE_J(j, hbp) { \
        const float gi = sigf(azi[j]); \
        const float gf = sigf(azf[j]); \
        const float gg = fmaxf(azg[j], 0.f); \
        const float go = sigf(azo[j]); \
        cst[j] = gf * cst[j] + gi * gg; \
        const float hj = go * fmaxf(cst[j], 0.f); \
        hbuf[pn][fg*4 + j][w*16 + fr] = hj; \
        hbp[(size_t)trow * 128] = hj; }
        GATE_J(0, hb0) GATE_J(1, hb1) GATE_J(2, hb2) GATE_J(3, hb3)
#undef GATE_J

        LDS_BAR();   // h[pn] visible to all waves; ONE barrier/step

        xcI = xnI; xcF = xnF; xcG = xnG; xcO = xnO;
        trow = trn;
        p = pn;
    }
}

// ---------------------------------------------------------------------------
// Dense + softmax: out[m][c] = softmax_c( h2[m][:] @ Wd[:,c] + bd[c] )
// ---------------------------------------------------------------------------
__global__ __launch_bounds__(256) void dense_softmax(
    const float* __restrict__ h2, const float* __restrict__ Wd,
    const float* __restrict__ bd, float* __restrict__ out)
{
    __shared__ float Wl[128 * 45];
    __shared__ float bl[48];
    __shared__ float hrow[4][128];
    const int tid = threadIdx.x;
    for (int i = tid; i < 128 * 45; i += 256) Wl[i] = Wd[i];
    if (tid < 45) bl[tid] = bd[tid];
    __syncthreads();

    const int w = tid >> 6, l = tid & 63;
    const size_t row0 = (size_t)blockIdx.x * 64;
    for (int rr = 0; rr < 16; ++rr) {
        const size_t m = row0 + (size_t)rr * 4 + w;
        const float2 hv = *(const float2*)&h2[m * 128 + l * 2];
        hrow[w][l * 2] = hv.x;
        hrow[w][l * 2 + 1] = hv.y;
        __syncthreads();
        float lg = -3.0e38f;
        if (l < CC) {
            lg = bl[l];
            #pragma unroll 8
            for (int k = 0; k < 128; ++k) lg = __fmaf_rn(hrow[w][k], Wl[k * 45 + l], lg);
        }
        float mx = lg;
        #pragma unroll
        for (int off = 32; off >= 1; off >>= 1) mx = fmaxf(mx, __shfl_xor(mx, off));
        const float e = (l < CC) ? __expf(lg - mx) : 0.f;
        float sm = e;
        #pragma unroll
        for (int off = 32; off >= 1; off >>= 1) sm += __shfl_xor(sm, off);
        if (l < CC) out[m * 45 + l] = e / sm;
        __syncthreads();
    }
}

// ---------------------------------------------------------------------------
extern "C" void kernel_launch(void* const* d_in, const int* in_sizes, int n_in,
                              void* d_out, int out_size, void* d_ws, size_t ws_size,
                              hipStream_t stream)
{
    const float* x   = (const float*)d_in[0];
    const float* W1f = (const float*)d_in[1];
    const float* U1f = (const float*)d_in[2];
    const float* b1f = (const float*)d_in[3];
    const float* W1b = (const float*)d_in[4];
    const float* U1b = (const float*)d_in[5];
    const float* b1b = (const float*)d_in[6];
    const float* W2f = (const float*)d_in[7];
    const float* U2f = (const float*)d_in[8];
    const float* b2f = (const float*)d_in[9];
    const float* W2b = (const float*)d_in[10];
    const float* U2b = (const float*)d_in[11];
    const float* b2b = (const float*)d_in[12];
    const float* Wd  = (const float*)d_in[13];
    const float* bd  = (const float*)d_in[14];

    // Workspace layout (160 MiB):
    //   xz : 65536 x 512 f32 = 128 MiB   (reused by layer 1 and layer 2)
    //   h  : 65536 x 128 f32 =  32 MiB   (h1, then overwritten by h2)
    float* xz = (float*)d_ws;
    float* h  = (float*)((char*)d_ws + (size_t)65536 * 512 * 4);

    const dim3 gemm_grid(4, 512);      // n-tile FASTEST (A-tile L2 sharing)
    const dim3 rec_grid(16);           // 2 dirs x 8 batch-groups of 16
    const dim3 dense_grid(1024);       // 65536/64 rows

    // Layer 1
    gemm_xz_mfma2<<<gemm_grid, dim3(256), 0, stream>>>(x, W1f, W1b, b1f, b1b, xz);
    lstm_rec_mm<<<rec_grid, dim3(256), 0, stream>>>(xz, U1f, U1b, h);
    // Layer 2
    gemm_xz_mfma2<<<gemm_grid, dim3(256), 0, stream>>>(h, W2f, W2b, b2f, b2b, xz);
    lstm_rec_mm<<<rec_grid, dim3(256), 0, stream>>>(xz, U2f, U2b, h);
    // Head
    dense_softmax<<<dense_grid, dim3(256), 0, stream>>>(h, Wd, bd, (float*)d_out);
}

// Round 17
// 707.989 us; speedup vs baseline: 1.6964x; 1.6964x over previous
//
#include <hip/hip_runtime.h>

#define TT 512
#define NB 128   // batch
#define DD 128
#define HH 64
#define CC 45

__device__ __forceinline__ float sigf(float x) { return 1.0f / (1.0f + __expf(-x)); }

// LDS-only barrier: syncs LDS visibility WITHOUT draining vmcnt.
#define LDS_BAR() asm volatile("s_waitcnt lgkmcnt(0)\n\ts_barrier" ::: "memory")

// Quad-lane xor via DPP quad_perm (VALU ~2cy; semantics proven R9/R12).
#define QP_XOR1(x) __int_as_float(__builtin_amdgcn_mov_dpp(__float_as_int(x), 0xB1, 0xF, 0xF, true))
#define QP_XOR2(x) __int_as_float(__builtin_amdgcn_mov_dpp(__float_as_int(x), 0x4E, 0xF, 0xF, true))

// bf16 helpers (RN rounding), ushort carries the bit pattern.
__device__ __forceinline__ ushort f2bf(float x) {
    uint u = __float_as_uint(x);
    u += 0x7FFFu + ((u >> 16) & 1u);
    return (ushort)(u >> 16);
}
__device__ __forceinline__ float bf2f(ushort h) { return __uint_as_float(((uint)h) << 16); }

typedef short short8 __attribute__((ext_vector_type(8)));
typedef float f32x4 __attribute__((ext_vector_type(4)));

// ---------------------------------------------------------------------------
// GEMM v2 via split-bf16 MFMA (R15, proven ~45us/dispatch).
// ---------------------------------------------------------------------------
__global__ __launch_bounds__(256, 2) void gemm_xz_mfma2(
    const float* __restrict__ A, const float* __restrict__ Wf,
    const float* __restrict__ Wb, const float* __restrict__ biasf,
    const float* __restrict__ biasb, float* __restrict__ Cout)
{
    __shared__ ushort Wh[128][136];
    __shared__ ushort Wl[128][136];

    const int tid = threadIdx.x;
    const int n0  = blockIdx.x * 128;
    const int m0  = blockIdx.y * 128;
    const float* W   = (n0 < 256) ? Wf : Wb;
    const float* bia = (n0 < 256) ? biasf : biasb;
    const int nc0 = n0 & 255;

    {
        const int r  = tid >> 1;
        const int cb = (tid & 1) * 64;
        #pragma unroll
        for (int i = 0; i < 16; ++i) {
            const int c = cb + i * 4;
            const float4 wv = *(const float4*)&W[(size_t)r * 256 + nc0 + c];
            const ushort h0 = (ushort)(__float_as_uint(wv.x) >> 16);
            const ushort h1 = (ushort)(__float_as_uint(wv.y) >> 16);
            const ushort h2 = (ushort)(__float_as_uint(wv.z) >> 16);
            const ushort h3 = (ushort)(__float_as_uint(wv.w) >> 16);
            Wh[c + 0][r] = h0; Wl[c + 0][r] = f2bf(wv.x - bf2f(h0));
            Wh[c + 1][r] = h1; Wl[c + 1][r] = f2bf(wv.y - bf2f(h1));
            Wh[c + 2][r] = h2; Wl[c + 2][r] = f2bf(wv.z - bf2f(h2));
            Wh[c + 3][r] = h3; Wl[c + 3][r] = f2bf(wv.w - bf2f(h3));
        }
    }
    __syncthreads();

    const int lane = tid & 63, wv_ = tid >> 6;
    const int fr = lane & 15, fg = lane >> 4;

    f32x4 acc[2][8];
    #pragma unroll
    for (int ms = 0; ms < 2; ++ms)
        #pragma unroll
        for (int nt = 0; nt < 8; ++nt) acc[ms][nt] = (f32x4){0.f, 0.f, 0.f, 0.f};

    #pragma unroll
    for (int ks = 0; ks < 4; ++ks) {
        const int kb = ks * 32 + fg * 8;
        short8 ah[2], al[2];
        #pragma unroll
        for (int ms = 0; ms < 2; ++ms) {
            const float* ap = &A[(size_t)(m0 + wv_ * 32 + ms * 16 + fr) * 128 + kb];
            const float4 va = *(const float4*)ap;
            const float4 vb = *(const float4*)(ap + 4);
            float v[8] = {va.x, va.y, va.z, va.w, vb.x, vb.y, vb.z, vb.w};
            #pragma unroll
            for (int j = 0; j < 8; ++j) {
                const ushort hj = (ushort)(__float_as_uint(v[j]) >> 16);
                ah[ms][j] = (short)hj;
                al[ms][j] = (short)f2bf(v[j] - bf2f(hj));
            }
        }
        #pragma unroll
        for (int nt = 0; nt < 8; ++nt) {
            const short8 bh = *(const short8*)&Wh[nt * 16 + fr][kb];
            const short8 bl = *(const short8*)&Wl[nt * 16 + fr][kb];
            acc[0][nt] = __builtin_amdgcn_mfma_f32_16x16x32_bf16(ah[0], bh, acc[0][nt], 0, 0, 0);
            acc[0][nt] = __builtin_amdgcn_mfma_f32_16x16x32_bf16(ah[0], bl, acc[0][nt], 0, 0, 0);
            acc[0][nt] = __builtin_amdgcn_mfma_f32_16x16x32_bf16(al[0], bh, acc[0][nt], 0, 0, 0);
            acc[1][nt] = __builtin_amdgcn_mfma_f32_16x16x32_bf16(ah[1], bh, acc[1][nt], 0, 0, 0);
            acc[1][nt] = __builtin_amdgcn_mfma_f32_16x16x32_bf16(ah[1], bl, acc[1][nt], 0, 0, 0);
            acc[1][nt] = __builtin_amdgcn_mfma_f32_16x16x32_bf16(al[1], bh, acc[1][nt], 0, 0, 0);
        }
    }

    #pragma unroll
    for (int nt = 0; nt < 8; ++nt) {
        const float bb = bia[nc0 + nt * 16 + fr];
        #pragma unroll
        for (int ms = 0; ms < 2; ++ms) {
            #pragma unroll
            for (int j = 0; j < 4; ++j) {
                const int mg = m0 + wv_ * 32 + ms * 16 + fg * 4 + j;
                Cout[(size_t)mg * 512 + n0 + nt * 16 + fr] = acc[ms][nt][j] + bb;
            }
        }
    }
}

// ---------------------------------------------------------------------------
// LSTM recurrence: resident-U (16/lane, R8-proven) + cheapest cross-lane.
// 256 blocks (batch x dir) x 1024 threads (16 waves, 4/SIMD).
// Lane bits: [1:0]=kq (DPP quad reduce), [3:2]=colL, [5:4]=gate (shfl16/32
// gather, R7/R8-proven selects). Wave owns cols w*4..w*4+3.
// Per lane: 16 U VGPRs (resident at this count: R8 VGPR=24), 16 FMA.
// Cross-lane per step: 2 quad_perm DPP adds (VALU) + 3 shfl (2 serial DS)
// vs R8's 5 serial DS shuffles; replicated gate math eliminated (each lane
// does ONE activation). ONE LDS_BAR/step; depth-2 xz prefetch;
// fire-and-forget h stores (never drained in-loop).
// ---------------------------------------------------------------------------
__global__ __launch_bounds__(1024, 1) void lstm_rec_qd(
    const float* __restrict__ xz, const float* __restrict__ Uf,
    const float* __restrict__ Ubw, float* __restrict__ hout)
{
    const int b   = blockIdx.x & 127;
    const int dir = blockIdx.x >> 7;
    const int tid = threadIdx.x;
    const int w    = tid >> 6;          // wave 0..15
    const int lane = tid & 63;
    const int kq   = lane & 3;          // K-quarter (quad -> DPP reduce)
    const int colL = (lane >> 2) & 3;
    const int gate = lane >> 4;         // 0:i 1:f 2:g 3:o (shfl gather)
    const int col  = w * 4 + colL;      // h column 0..63
    const int gcol = gate * 64 + col;
    const float* U = dir ? Ubw : Uf;

    __shared__ float hbuf[2][64];

    // 16 U values: U[kq*16 + j][gcol], pinned (R8-proven resident).
    const float* Ug = U + (size_t)(kq * 16) * 256 + gcol;
    float u0  = Ug[0 * 256],  u1  = Ug[1 * 256],  u2  = Ug[2 * 256],  u3  = Ug[3 * 256];
    float u4  = Ug[4 * 256],  u5  = Ug[5 * 256],  u6  = Ug[6 * 256],  u7  = Ug[7 * 256];
    float u8  = Ug[8 * 256],  u9  = Ug[9 * 256],  u10 = Ug[10 * 256], u11 = Ug[11 * 256];
    float u12 = Ug[12 * 256], u13 = Ug[13 * 256], u14 = Ug[14 * 256], u15 = Ug[15 * 256];
    asm volatile("" : "+v"(u0), "+v"(u1), "+v"(u2), "+v"(u3),
                      "+v"(u4), "+v"(u5), "+v"(u6), "+v"(u7),
                      "+v"(u8), "+v"(u9), "+v"(u10), "+v"(u11),
                      "+v"(u12), "+v"(u13), "+v"(u14), "+v"(u15));

    if (tid < 64) hbuf[0][tid] = 0.f;
    float c = 0.f;
    __syncthreads();

    const float* xzb = xz + (size_t)b * TT * 512 + (size_t)dir * 256 + gcol;
    float*       hob = hout + (size_t)b * TT * 128 + (size_t)dir * 64 + col;

    int trow = dir ? (TT - 1) : 0;
    const int ts = dir ? -1 : 1;
    float xc = xzb[(size_t)trow * 512];            // step s
    float x1 = xzb[(size_t)(trow + ts) * 512];     // step s+1

    for (int s = 0; s < TT; ++s) {
        const int p = s & 1;
        float x2 = 0.f;
        if (s + 2 < TT) x2 = xzb[(size_t)(trow + 2 * ts) * 512];  // depth-2

        // 16-FMA partial over this lane's K-quarter. Per-wave: 4 distinct
        // 16B addrs (kq groups); bank aliasing 2-way = free (m136).
        const float4 h0 = *(const float4*)&hbuf[p][kq * 16 + 0];
        const float4 h1 = *(const float4*)&hbuf[p][kq * 16 + 4];
        const float4 h2 = *(const float4*)&hbuf[p][kq * 16 + 8];
        const float4 h3 = *(const float4*)&hbuf[p][kq * 16 + 12];
        float a0 = 0.f, a1 = 0.f, a2 = 0.f, a3 = 0.f;
        a0 = __fmaf_rn(h0.x, u0,  a0); a1 = __fmaf_rn(h0.y, u1,  a1);
        a2 = __fmaf_rn(h0.z, u2,  a2); a3 = __fmaf_rn(h0.w, u3,  a3);
        a0 = __fmaf_rn(h1.x, u4,  a0); a1 = __fmaf_rn(h1.y, u5,  a1);
        a2 = __fmaf_rn(h1.z, u6,  a2); a3 = __fmaf_rn(h1.w, u7,  a3);
        a0 = __fmaf_rn(h2.x, u8,  a0); a1 = __fmaf_rn(h2.y, u9,  a1);
        a2 = __fmaf_rn(h2.z, u10, a2); a3 = __fmaf_rn(h2.w, u11, a3);
        a0 = __fmaf_rn(h3.x, u12, a0); a1 = __fmaf_rn(h3.y, u13, a1);
        a2 = __fmaf_rn(h3.z, u14, a2); a3 = __fmaf_rn(h3.w, u15, a3);
        float part = (a0 + a1) + (a2 + a3);

        // kq-reduce within the quad: 2 DPP adds (VALU-speed, proven ops)
        part += QP_XOR1(part);
        part += QP_XOR2(part);
        const float z = xc + part;      // xc identical across the 4 kq lanes

        // own gate's activation (relu for gate 2, sigmoid otherwise)
        const float a = (gate == 2) ? fmaxf(z, 0.f) : sigf(z);

        // gate all-gather over lane bits [5:4] (R7/R8-proven formulas)
        const float b0 = __shfl_xor(a, 16);
        const float b1 = __shfl_xor(a, 32);
        const float b2 = __shfl_xor(b0, 32);
        const float ai = (gate == 0) ? a : (gate == 1) ? b0 : (gate == 2) ? b1 : b2;
        const float af = (gate == 1) ? a : (gate == 0) ? b0 : (gate == 3) ? b1 : b2;
        const float ag = (gate == 2) ? a : (gate == 3) ? b0 : (gate == 0) ? b1 : b2;
        const float ao = (gate == 3) ? a : (gate == 2) ? b0 : (gate == 1) ? b1 : b2;

        // replicated state update (all 16 lanes of a column agree)
        c = af * c + ai * ag;            // ag already relu'd
        const float h = ao * fmaxf(c, 0.f);

        if ((lane & 0x33) == 0) {        // writer: kq==0 && gate==0
            hbuf[p ^ 1][col] = h;
            hob[(size_t)trow * 128] = h; // fire-and-forget, never drained
        }

        LDS_BAR();                       // ONE barrier/step; WAR safe (parity)

        xc = x1; x1 = x2;
        trow += ts;
    }
}

// ---------------------------------------------------------------------------
// Dense + softmax: out[m][c] = softmax_c( h2[m][:] @ Wd[:,c] + bd[c] )
// ---------------------------------------------------------------------------
__global__ __launch_bounds__(256) void dense_softmax(
    const float* __restrict__ h2, const float* __restrict__ Wd,
    const float* __restrict__ bd, float* __restrict__ out)
{
    __shared__ float Wl[128 * 45];
    __shared__ float bl[48];
    __shared__ float hrow[4][128];
    const int tid = threadIdx.x;
    for (int i = tid; i < 128 * 45; i += 256) Wl[i] = Wd[i];
    if (tid < 45) bl[tid] = bd[tid];
    __syncthreads();

    const int w = tid >> 6, l = tid & 63;
    const size_t row0 = (size_t)blockIdx.x * 64;
    for (int rr = 0; rr < 16; ++rr) {
        const size_t m = row0 + (size_t)rr * 4 + w;
        const float2 hv = *(const float2*)&h2[m * 128 + l * 2];
        hrow[w][l * 2] = hv.x;
        hrow[w][l * 2 + 1] = hv.y;
        __syncthreads();
        float lg = -3.0e38f;
        if (l < CC) {
            lg = bl[l];
            #pragma unroll 8
            for (int k = 0; k < 128; ++k) lg = __fmaf_rn(hrow[w][k], Wl[k * 45 + l], lg);
        }
        float mx = lg;
        #pragma unroll
        for (int off = 32; off >= 1; off >>= 1) mx = fmaxf(mx, __shfl_xor(mx, off));
        const float e = (l < CC) ? __expf(lg - mx) : 0.f;
        float sm = e;
        #pragma unroll
        for (int off = 32; off >= 1; off >>= 1) sm += __shfl_xor(sm, off);
        if (l < CC) out[m * 45 + l] = e / sm;
        __syncthreads();
    }
}

// ---------------------------------------------------------------------------
extern "C" void kernel_launch(void* const* d_in, const int* in_sizes, int n_in,
                              void* d_out, int out_size, void* d_ws, size_t ws_size,
                              hipStream_t stream)
{
    const float* x   = (const float*)d_in[0];
    const float* W1f = (const float*)d_in[1];
    const float* U1f = (const float*)d_in[2];
    const float* b1f = (const float*)d_in[3];
    const float* W1b = (const float*)d_in[4];
    const float* U1b = (const float*)d_in[5];
    const float* b1b = (const float*)d_in[6];
    const float* W2f = (const float*)d_in[7];
    const float* U2f = (const float*)d_in[8];
    const float* b2f = (const float*)d_in[9];
    const float* W2b = (const float*)d_in[10];
    const float* U2b = (const float*)d_in[11];
    const float* b2b = (const float*)d_in[12];
    const float* Wd  = (const float*)d_in[13];
    const float* bd  = (const float*)d_in[14];

    // Workspace layout (160 MiB):
    //   xz : 65536 x 512 f32 = 128 MiB   (reused by layer 1 and layer 2)
    //   h  : 65536 x 128 f32 =  32 MiB   (h1, then overwritten by h2)
    float* xz = (float*)d_ws;
    float* h  = (float*)((char*)d_ws + (size_t)65536 * 512 * 4);

    const dim3 gemm_grid(4, 512);      // n-tile FASTEST (A-tile L2 sharing)
    const dim3 rec_grid(256);          // 128 batch x 2 directions
    const dim3 dense_grid(1024);       // 65536/64 rows

    // Layer 1
    gemm_xz_mfma2<<<gemm_grid, dim3(256), 0, stream>>>(x, W1f, W1b, b1f, b1b, xz);
    lstm_rec_qd<<<rec_grid, dim3(1024), 0, stream>>>(xz, U1f, U1b, h);
    // Layer 2
    gemm_xz_mfma2<<<gemm_grid, dim3(256), 0, stream>>>(h, W2f, W2b, b2f, b2b, xz);
    lstm_rec_qd<<<rec_grid, dim3(1024), 0, stream>>>(xz, U2f, U2b, h);
    // Head
    dense_softmax<<<dense_grid, dim3(256), 0, stream>>>(h, Wd, bd, (float*)d_out);
}